// Round 5
// baseline (1317.310 us; speedup 1.0000x reference)
//
#include <hip/hip_runtime.h>
#include <hip/hip_bf16.h>

#define N_NODES 100000
#define N_EDGES 3200000
#define N_GRAPHS 512
#define HID 64
#define OUT_DIM 10

#define NPB 98                  // nodes per dst-bucket
#define NB  1021                // ceil(N_NODES / NPB)
#define CAP 3584                // edges/bucket capacity (mean 3136, sd ~56 -> +8 sigma)

// ---------------------------------------------------------------------------
// K1: partition edges into dst-range buckets. Packed word: (dlocal<<24)|src.
// Block-aggregated cursors: LDS histogram -> 1 ranged global atomic per
// (block,bucket) -> LDS cursors -> append. Writes are time-coalesced.
__global__ __launch_bounds__(256) void k_part(const int4* __restrict__ src4,
                                              const int4* __restrict__ dst4,
                                              unsigned* __restrict__ bcur,
                                              unsigned* __restrict__ ebuf) {
    __shared__ unsigned hist[NB];
    __shared__ unsigned curs[NB];
    int tid = threadIdx.x;
    for (int i = tid; i < NB; i += 256) hist[i] = 0;
    __syncthreads();
    // stage 16 edges (4 x int4) in registers
    int4 s[4], d[4];
    int base4 = (blockIdx.x * 256 + tid) * 4;
    #pragma unroll
    for (int k = 0; k < 4; k++) {
        int i4 = base4 + k;
        if (i4 < N_EDGES / 4) { s[k] = src4[i4]; d[k] = dst4[i4]; }
        else { s[k] = make_int4(-1, -1, -1, -1); d[k] = make_int4(0, 0, 0, 0); }
    }
    #pragma unroll
    for (int k = 0; k < 4; k++) {
        if (s[k].x >= 0) {
            atomicAdd(&hist[d[k].x / NPB], 1u);
            atomicAdd(&hist[d[k].y / NPB], 1u);
            atomicAdd(&hist[d[k].z / NPB], 1u);
            atomicAdd(&hist[d[k].w / NPB], 1u);
        }
    }
    __syncthreads();
    for (int b = tid; b < NB; b += 256) {
        unsigned c = hist[b];
        curs[b] = c ? atomicAdd(&bcur[b], c) : 0u;
    }
    __syncthreads();
    #pragma unroll
    for (int k = 0; k < 4; k++) {
        if (s[k].x >= 0) {
            int ss[4] = { s[k].x, s[k].y, s[k].z, s[k].w };
            int dd[4] = { d[k].x, d[k].y, d[k].z, d[k].w };
            #pragma unroll
            for (int m = 0; m < 4; m++) {
                int b = dd[m] / NPB;
                unsigned dl = (unsigned)(dd[m] - b * NPB);
                unsigned slot = atomicAdd(&curs[b], 1u);
                ebuf[(size_t)b * CAP + slot] = (dl << 24) | (unsigned)ss[m];
            }
        }
    }
}

// ---------------------------------------------------------------------------
// K2: per-bucket degree histogram in LDS -> dinv, g1 (all in-edges of a node
// live in its bucket, so degree completes locally; no global atomics).
__global__ __launch_bounds__(256) void k_buck1(const unsigned* __restrict__ ebuf,
                                               const unsigned* __restrict__ bcur,
                                               const float* __restrict__ x,
                                               float* __restrict__ dinv,
                                               float* __restrict__ g1) {
    __shared__ unsigned cnt[NPB];
    int b = blockIdx.x, tid = threadIdx.x;
    if (tid < NPB) cnt[tid] = 0;
    __syncthreads();
    int ec = (int)bcur[b];
    const unsigned* eb = ebuf + (size_t)b * CAP;
    for (int i = tid; i < ec; i += 256)
        atomicAdd(&cnt[eb[i] >> 24], 1u);
    __syncthreads();
    int n0 = b * NPB;
    int nn = min(NPB, N_NODES - n0);
    if (tid < nn) {
        float dn = 1.0f / sqrtf((float)cnt[tid] + 1.0f);   // +1: self loop
        dinv[n0 + tid] = dn;
        g1[n0 + tid] = dn * x[n0 + tid];
    }
}

// ---------------------------------------------------------------------------
// K3: per-bucket layer-1 scalar aggregation in LDS -> sd = (s, dinv).
__global__ __launch_bounds__(256) void k_buck2(const unsigned* __restrict__ ebuf,
                                               const unsigned* __restrict__ bcur,
                                               const float* __restrict__ g1,
                                               const float* __restrict__ dinv,
                                               const float* __restrict__ x,
                                               float2* __restrict__ sd) {
    __shared__ float sacc[NPB];
    int b = blockIdx.x, tid = threadIdx.x;
    if (tid < NPB) sacc[tid] = 0.f;
    __syncthreads();
    int ec = (int)bcur[b];
    const unsigned* eb = ebuf + (size_t)b * CAP;
    for (int i = tid; i < ec; i += 256) {
        unsigned w = eb[i];
        atomicAdd(&sacc[w >> 24], g1[w & 0x00FFFFFFu]);
    }
    __syncthreads();
    int n0 = b * NPB;
    int nn = min(NPB, N_NODES - n0);
    if (tid < nn) {
        float dn = dinv[n0 + tid];
        float s = dn * (sacc[tid] + dn * x[n0 + tid]);
        sd[n0 + tid] = make_float2(s, dn);
    }
}

// ---------------------------------------------------------------------------
// K4: per-bucket layer-2 aggregation, LANE-PARALLEL over edges. Each lane owns
// one edge: coalesced packed-word load + one 8B sd gather, then a 64-step
// rotated-channel register loop: lane l at step j updates channel (l+j)&63 of
// its edge's dst row via ds_add_f32. Rotation => banks = ch%32 (benign 2-way),
// and zero same-address collisions within the wave. Fused self-term + W2
// matvec (shfl broadcast) + relu -> x2.
__global__ __launch_bounds__(256) void k_buck3(const unsigned* __restrict__ ebuf,
                                               const unsigned* __restrict__ bcur,
                                               const float2* __restrict__ sd,
                                               const float* __restrict__ W1,
                                               const float* __restrict__ b1,
                                               const float* __restrict__ W2,
                                               const float* __restrict__ b2,
                                               float* __restrict__ x2) {
    __shared__ float agg[NPB * HID];   // 25088 B
    __shared__ float2 wb[HID];         // (W1[j], b1[j])
    int b = blockIdx.x, tid = threadIdx.x;
    int lane = tid & 63, wv = tid >> 6;
    for (int i = tid; i < NPB * HID; i += 256) agg[i] = 0.f;
    if (tid < HID) wb[tid] = make_float2(W1[tid], b1[tid]);
    __syncthreads();
    int ec = (int)bcur[b];
    const unsigned* eb = ebuf + (size_t)b * CAP;
    // per-wave contiguous slice of this bucket's edges
    int lo = (ec * wv) >> 2;
    int hi = (ec * (wv + 1)) >> 2;
    for (int base = lo; base < hi; base += 64) {
        int i = base + lane;
        if (i < hi) {
            unsigned w = eb[i];                  // coalesced
            float2 v = sd[w & 0x00FFFFFFu];      // 8B gather, L2-resident
            int aggbase = (int)(w >> 24) * HID;
            #pragma unroll 16
            for (int j = 0; j < HID; j++) {
                int ch = (lane + j) & 63;
                float2 c = wb[ch];
                float t = fmaxf(fmaf(v.x, c.x, c.y), 0.f);
                atomicAdd(&agg[aggbase + ch], v.y * t);
            }
        }
    }
    __syncthreads();
    int n0 = b * NPB;
    int nn = min(NPB, N_NODES - n0);
    float2 wbl = wb[lane];
    for (int n = wv; n < nn; n += 4) {
        float2 self = sd[n0 + n];
        float t = fmaxf(fmaf(self.x, wbl.x, wbl.y), 0.f);
        float a = self.y * (agg[n * HID + lane] + self.y * t);
        float acc2 = b2[lane];
        #pragma unroll 8
        for (int j = 0; j < HID; j++) {
            float aj = __shfl(a, j, 64);
            acc2 = fmaf(aj, W2[j * HID + lane], acc2);
        }
        x2[(size_t)(n0 + n) * HID + lane] = fmaxf(acc2, 0.f);
    }
}

// ---------------------------------------------------------------------------
// K5: graph segment boundaries from sorted batch.
__global__ void k_bounds(const int* __restrict__ batch, int* __restrict__ gstart) {
    int i = blockIdx.x * blockDim.x + threadIdx.x;
    if (i >= N_NODES) return;
    int b = batch[i];
    if (i == 0) {
        for (int g = 0; g <= b; g++) gstart[g] = 0;
    } else {
        int pb = batch[i - 1];
        for (int g = pb + 1; g <= b; g++) gstart[g] = i;
    }
    if (i == N_NODES - 1) {
        for (int g = b + 1; g <= N_GRAPHS; g++) gstart[g] = N_NODES;
    }
}

// K6: fused mean-pool + linear head. One block (256 thr) per graph.
__global__ __launch_bounds__(256) void k_pool(const float* __restrict__ x2,
                                              const float2* __restrict__ sd,
                                              const float* __restrict__ W1,
                                              const float* __restrict__ b1,
                                              const int* __restrict__ gstart,
                                              const float* __restrict__ Wl,
                                              const float* __restrict__ bl,
                                              float* __restrict__ out) {
    int g = blockIdx.x;
    int t = threadIdx.x;
    int c = t & 127;
    int part = t >> 7;
    int lo = gstart[g], hi = gstart[g + 1];
    float w = 0.f, b = 0.f;
    if (c < HID) { w = W1[c]; b = b1[c]; }
    float acc = 0.f;
    if (c < HID) {
        for (int n = lo + part; n < hi; n += 2)
            acc += fmaxf(fmaf(sd[n].x, w, b), 0.f);
    } else {
        int j = c - HID;
        for (int n = lo + part; n < hi; n += 2)
            acc += x2[(size_t)n * HID + j];
    }
    __shared__ float pl[2 * HID];
    if (part == 0) pl[c] = acc;
    __syncthreads();
    if (part == 1) pl[c] += acc;
    __syncthreads();
    if (t < 2 * HID) pl[t] /= fmaxf((float)(hi - lo), 1.f);
    __syncthreads();
    if (t < OUT_DIM) {
        float r = bl[t];
        #pragma unroll 16
        for (int j = 0; j < 2 * HID; j++) r = fmaf(pl[j], Wl[j * OUT_DIM + t], r);
        out[g * OUT_DIM + t] = r;
    }
}

// ---------------------------------------------------------------------------
extern "C" void kernel_launch(void* const* d_in, const int* in_sizes, int n_in,
                              void* d_out, int out_size, void* d_ws, size_t ws_size,
                              hipStream_t stream) {
    const float* x      = (const float*)d_in[0];
    const int*   ei     = (const int*)d_in[1];           // (2, E) int32
    const int*   batch  = (const int*)d_in[2];
    const float* W1     = (const float*)d_in[3];
    const float* b1     = (const float*)d_in[4];
    const float* W2     = (const float*)d_in[5];
    const float* b2     = (const float*)d_in[6];
    const float* Wl     = (const float*)d_in[7];
    const float* bl     = (const float*)d_in[8];
    float* out = (float*)d_out;

    const int* src = ei;
    const int* dst = ei + N_EDGES;

    // workspace carve-up (256B aligned)
    char* p = (char*)d_ws;
    auto alloc = [&](size_t bytes) { void* r = (void*)p; p += (bytes + 255) & ~(size_t)255; return r; };
    unsigned* bcur   = (unsigned*)alloc(NB * 4);
    unsigned* ebuf   = (unsigned*)alloc((size_t)NB * CAP * 4);   // 14.64 MB
    float*    dinv   = (float*)alloc(N_NODES * 4);
    float*    g1     = (float*)alloc(N_NODES * 4);
    float2*   sd     = (float2*)alloc((size_t)N_NODES * 8);
    float*    x2     = (float*)alloc((size_t)N_NODES * HID * 4);
    int*      gstart = (int*)alloc((N_GRAPHS + 1) * 4);

    hipMemsetAsync(bcur, 0, NB * 4, stream);

    const int TB = 256;
    int pbl = (N_EDGES / 16 + TB - 1) / TB;   // 16 edges per thread
    int nbl = (N_NODES + TB - 1) / TB;

    k_part <<<pbl, TB, 0, stream>>>((const int4*)src, (const int4*)dst, bcur, ebuf);
    k_buck1<<<NB, TB, 0, stream>>>(ebuf, bcur, x, dinv, g1);
    k_buck2<<<NB, TB, 0, stream>>>(ebuf, bcur, g1, dinv, x, sd);
    k_buck3<<<NB, TB, 0, stream>>>(ebuf, bcur, sd, W1, b1, W2, b2, x2);
    k_bounds<<<nbl, TB, 0, stream>>>(batch, gstart);
    k_pool <<<N_GRAPHS, TB, 0, stream>>>(x2, sd, W1, b1, gstart, Wl, bl, out);
}

// Round 7
// 262.176 us; speedup vs baseline: 5.0245x; 5.0245x over previous
//
#include <hip/hip_runtime.h>
#include <hip/hip_bf16.h>

#define N_NODES 100000
#define N_EDGES 3200000
#define N_GRAPHS 512
#define HID 64
#define OUT_DIM 10

#define NPB 98                  // nodes per dst-bucket
#define NB  1021                // ceil(N_NODES / NPB)
#define CAP 3584                // edges/bucket capacity (mean 3136, sd ~56 -> +8 sigma)

// ---------------------------------------------------------------------------
// K1: partition edges into dst-range buckets. Packed word: (dlocal<<24)|src.
// Block-aggregated cursors: LDS histogram -> 1 ranged global atomic per
// (block,bucket) -> LDS cursors -> append. Writes are time-coalesced.
__global__ __launch_bounds__(256) void k_part(const int4* __restrict__ src4,
                                              const int4* __restrict__ dst4,
                                              unsigned* __restrict__ bcur,
                                              unsigned* __restrict__ ebuf) {
    __shared__ unsigned hist[NB];
    __shared__ unsigned curs[NB];
    int tid = threadIdx.x;
    for (int i = tid; i < NB; i += 256) hist[i] = 0;
    __syncthreads();
    // stage 16 edges (4 x int4) in registers
    int4 s[4], d[4];
    int base4 = (blockIdx.x * 256 + tid) * 4;
    #pragma unroll
    for (int k = 0; k < 4; k++) {
        int i4 = base4 + k;
        if (i4 < N_EDGES / 4) { s[k] = src4[i4]; d[k] = dst4[i4]; }
        else { s[k] = make_int4(-1, -1, -1, -1); d[k] = make_int4(0, 0, 0, 0); }
    }
    #pragma unroll
    for (int k = 0; k < 4; k++) {
        if (s[k].x >= 0) {
            atomicAdd(&hist[d[k].x / NPB], 1u);
            atomicAdd(&hist[d[k].y / NPB], 1u);
            atomicAdd(&hist[d[k].z / NPB], 1u);
            atomicAdd(&hist[d[k].w / NPB], 1u);
        }
    }
    __syncthreads();
    for (int b = tid; b < NB; b += 256) {
        unsigned c = hist[b];
        curs[b] = c ? atomicAdd(&bcur[b], c) : 0u;
    }
    __syncthreads();
    #pragma unroll
    for (int k = 0; k < 4; k++) {
        if (s[k].x >= 0) {
            int ss[4] = { s[k].x, s[k].y, s[k].z, s[k].w };
            int dd[4] = { d[k].x, d[k].y, d[k].z, d[k].w };
            #pragma unroll
            for (int m = 0; m < 4; m++) {
                int b = dd[m] / NPB;
                unsigned dl = (unsigned)(dd[m] - b * NPB);
                unsigned slot = atomicAdd(&curs[b], 1u);
                ebuf[(size_t)b * CAP + slot] = (dl << 24) | (unsigned)ss[m];
            }
        }
    }
}

// ---------------------------------------------------------------------------
// K2: per-bucket degree histogram in LDS -> deg, dinv, g1 (all in-edges of a
// node live in its bucket, so degree completes locally; no global atomics).
__global__ __launch_bounds__(256) void k_buck1(const unsigned* __restrict__ ebuf,
                                               const unsigned* __restrict__ bcur,
                                               const float* __restrict__ x,
                                               unsigned* __restrict__ deg,
                                               float* __restrict__ dinv,
                                               float* __restrict__ g1) {
    __shared__ unsigned cnt[NPB];
    int b = blockIdx.x, tid = threadIdx.x;
    if (tid < NPB) cnt[tid] = 0;
    __syncthreads();
    int ec = (int)bcur[b];
    const unsigned* eb = ebuf + (size_t)b * CAP;
    for (int i = tid; i < ec; i += 256)
        atomicAdd(&cnt[eb[i] >> 24], 1u);
    __syncthreads();
    int n0 = b * NPB;
    int nn = min(NPB, N_NODES - n0);
    if (tid < nn) {
        unsigned c = cnt[tid];
        float dn = 1.0f / sqrtf((float)c + 1.0f);   // +1: self loop
        deg[n0 + tid] = c;
        dinv[n0 + tid] = dn;
        g1[n0 + tid] = dn * x[n0 + tid];
    }
}

// ---------------------------------------------------------------------------
// K3: per-bucket layer-1 scalar aggregation in LDS -> sd = (s, dinv).
__global__ __launch_bounds__(256) void k_buck2(const unsigned* __restrict__ ebuf,
                                               const unsigned* __restrict__ bcur,
                                               const float* __restrict__ g1,
                                               const float* __restrict__ dinv,
                                               const float* __restrict__ x,
                                               float2* __restrict__ sd) {
    __shared__ float sacc[NPB];
    int b = blockIdx.x, tid = threadIdx.x;
    if (tid < NPB) sacc[tid] = 0.f;
    __syncthreads();
    int ec = (int)bcur[b];
    const unsigned* eb = ebuf + (size_t)b * CAP;
    for (int i = tid; i < ec; i += 256) {
        unsigned w = eb[i];
        atomicAdd(&sacc[w >> 24], g1[w & 0x00FFFFFFu]);
    }
    __syncthreads();
    int n0 = b * NPB;
    int nn = min(NPB, N_NODES - n0);
    if (tid < nn) {
        float dn = dinv[n0 + tid];
        float s = dn * (sacc[tid] + dn * x[n0 + tid]);
        sd[n0 + tid] = make_float2(s, dn);
    }
}

// ---------------------------------------------------------------------------
// K4: per-bucket layer-2 aggregation, ATOMIC-FREE hot loop.
// 1) counting-sort bucket edges by dlocal into LDS (int ds_add_rtn: cheap),
// 2) wave-per-node: lanes batch-gather 64 (s,dinv) pairs -> wave-private LDS
//    stage -> broadcast-read loop accumulates in registers (lane = channel),
// 3) fused self-term + W2 matvec with W2 column in VGPRs + readlane
//    broadcasts (SALU) -> relu -> x2.  Zero LDS atomics per edge.
__global__ __launch_bounds__(256) void k_buck3(const unsigned* __restrict__ ebuf,
                                               const unsigned* __restrict__ bcur,
                                               const unsigned* __restrict__ deg,
                                               const float2* __restrict__ sd,
                                               const float* __restrict__ W1,
                                               const float* __restrict__ b1,
                                               const float* __restrict__ W2,
                                               const float* __restrict__ b2,
                                               float* __restrict__ x2) {
    __shared__ unsigned sorted[CAP];     // 14336 B
    __shared__ float2 stage[256];        // 4 waves x 64, wave-private slices
    __shared__ int offs[NPB + 1];
    __shared__ unsigned curs[NPB];
    int b = blockIdx.x, tid = threadIdx.x;
    int lane = tid & 63, wv = tid >> 6;
    int n0 = b * NPB;
    int nn = min(NPB, N_NODES - n0);
    if (tid == 0) {                      // serial 98-scan: ~800 cy, negligible
        int r = 0;
        for (int i = 0; i < nn; i++) { offs[i] = r; curs[i] = (unsigned)r; r += (int)deg[n0 + i]; }
        offs[nn] = r;
    }
    // W2 column + per-lane constants while tid0 scans
    float w2col[HID];
    #pragma unroll
    for (int j = 0; j < HID; j++) w2col[j] = W2[j * HID + lane];
    float w1 = W1[lane], bb1 = b1[lane], bb2 = b2[lane];
    __syncthreads();
    int ec = (int)bcur[b];
    const unsigned* eb = ebuf + (size_t)b * CAP;
    for (int i = tid; i < ec; i += 256) {           // counting-sort scatter
        unsigned w = eb[i];
        unsigned slot = atomicAdd(&curs[w >> 24], 1u);   // int LDS atomic
        sorted[slot] = w;
    }
    __syncthreads();
    float2* st = stage + wv * 64;
    for (int n = wv; n < nn; n += 4) {
        int lo = offs[n], hi = offs[n + 1];
        float acca = 0.f, accb = 0.f;
        for (int base = lo; base < hi; base += 64) {
            int m = hi - base; if (m > 64) m = 64;
            float2 v = make_float2(0.f, 0.f);
            if (lane < m) v = sd[sorted[base + lane] & 0x00FFFFFFu];  // batched gather
            st[lane] = v;                 // wave-private; DS ops in-order per wave
            int k = 0;
            for (; k + 1 < m; k += 2) {   // broadcast reads, 2-way acc split
                float2 e0 = st[k];
                float2 e1 = st[k + 1];
                acca = fmaf(e0.y, fmaxf(fmaf(e0.x, w1, bb1), 0.f), acca);
                accb = fmaf(e1.y, fmaxf(fmaf(e1.x, w1, bb1), 0.f), accb);
            }
            if (k < m) {
                float2 e0 = st[k];
                acca = fmaf(e0.y, fmaxf(fmaf(e0.x, w1, bb1), 0.f), acca);
            }
        }
        float2 self = sd[n0 + n];
        float t = fmaxf(fmaf(self.x, w1, bb1), 0.f);
        float a = self.y * (acca + accb + self.y * t);   // agg[n][lane]
        // x2 = relu(a_row @ W2 + b2): readlane broadcast (SALU) + reg W2
        float acc2a = bb2, acc2b = 0.f;
        #pragma unroll
        for (int j = 0; j < HID; j += 2) {
            float aj0 = __int_as_float(__builtin_amdgcn_readlane(__float_as_int(a), j));
            float aj1 = __int_as_float(__builtin_amdgcn_readlane(__float_as_int(a), j + 1));
            acc2a = fmaf(aj0, w2col[j], acc2a);
            acc2b = fmaf(aj1, w2col[j + 1], acc2b);
        }
        x2[(size_t)(n0 + n) * HID + lane] = fmaxf(acc2a + acc2b, 0.f);
    }
}

// ---------------------------------------------------------------------------
// K5: graph segment boundaries from sorted batch.
__global__ void k_bounds(const int* __restrict__ batch, int* __restrict__ gstart) {
    int i = blockIdx.x * blockDim.x + threadIdx.x;
    if (i >= N_NODES) return;
    int b = batch[i];
    if (i == 0) {
        for (int g = 0; g <= b; g++) gstart[g] = 0;
    } else {
        int pb = batch[i - 1];
        for (int g = pb + 1; g <= b; g++) gstart[g] = i;
    }
    if (i == N_NODES - 1) {
        for (int g = b + 1; g <= N_GRAPHS; g++) gstart[g] = N_NODES;
    }
}

// K6: fused mean-pool + linear head. One block (256 thr) per graph.
__global__ __launch_bounds__(256) void k_pool(const float* __restrict__ x2,
                                              const float2* __restrict__ sd,
                                              const float* __restrict__ W1,
                                              const float* __restrict__ b1,
                                              const int* __restrict__ gstart,
                                              const float* __restrict__ Wl,
                                              const float* __restrict__ bl,
                                              float* __restrict__ out) {
    int g = blockIdx.x;
    int t = threadIdx.x;
    int c = t & 127;
    int part = t >> 7;
    int lo = gstart[g], hi = gstart[g + 1];
    float w = 0.f, b = 0.f;
    if (c < HID) { w = W1[c]; b = b1[c]; }
    float acc = 0.f;
    if (c < HID) {
        for (int n = lo + part; n < hi; n += 2)
            acc += fmaxf(fmaf(sd[n].x, w, b), 0.f);
    } else {
        int j = c - HID;
        for (int n = lo + part; n < hi; n += 2)
            acc += x2[(size_t)n * HID + j];
    }
    __shared__ float pl[2 * HID];
    if (part == 0) pl[c] = acc;
    __syncthreads();
    if (part == 1) pl[c] += acc;
    __syncthreads();
    if (t < 2 * HID) pl[t] /= fmaxf((float)(hi - lo), 1.f);
    __syncthreads();
    if (t < OUT_DIM) {
        float r = bl[t];
        #pragma unroll 16
        for (int j = 0; j < 2 * HID; j++) r = fmaf(pl[j], Wl[j * OUT_DIM + t], r);
        out[g * OUT_DIM + t] = r;
    }
}

// ---------------------------------------------------------------------------
extern "C" void kernel_launch(void* const* d_in, const int* in_sizes, int n_in,
                              void* d_out, int out_size, void* d_ws, size_t ws_size,
                              hipStream_t stream) {
    const float* x      = (const float*)d_in[0];
    const int*   ei     = (const int*)d_in[1];           // (2, E) int32
    const int*   batch  = (const int*)d_in[2];
    const float* W1     = (const float*)d_in[3];
    const float* b1     = (const float*)d_in[4];
    const float* W2     = (const float*)d_in[5];
    const float* b2     = (const float*)d_in[6];
    const float* Wl     = (const float*)d_in[7];
    const float* bl     = (const float*)d_in[8];
    float* out = (float*)d_out;

    const int* src = ei;
    const int* dst = ei + N_EDGES;

    // workspace carve-up (256B aligned)
    char* p = (char*)d_ws;
    auto alloc = [&](size_t bytes) { void* r = (void*)p; p += (bytes + 255) & ~(size_t)255; return r; };
    unsigned* bcur   = (unsigned*)alloc(NB * 4);
    unsigned* ebuf   = (unsigned*)alloc((size_t)NB * CAP * 4);   // 14.64 MB
    unsigned* deg    = (unsigned*)alloc(N_NODES * 4);
    float*    dinv   = (float*)alloc(N_NODES * 4);
    float*    g1     = (float*)alloc(N_NODES * 4);
    float2*   sd     = (float2*)alloc((size_t)N_NODES * 8);
    float*    x2     = (float*)alloc((size_t)N_NODES * HID * 4);
    int*      gstart = (int*)alloc((N_GRAPHS + 1) * 4);

    hipMemsetAsync(bcur, 0, NB * 4, stream);

    const int TB = 256;
    int pbl = (N_EDGES / 16 + TB - 1) / TB;   // 16 edges per thread
    int nbl = (N_NODES + TB - 1) / TB;

    k_part <<<pbl, TB, 0, stream>>>((const int4*)src, (const int4*)dst, bcur, ebuf);
    k_buck1<<<NB, TB, 0, stream>>>(ebuf, bcur, x, deg, dinv, g1);
    k_buck2<<<NB, TB, 0, stream>>>(ebuf, bcur, g1, dinv, x, sd);
    k_buck3<<<NB, TB, 0, stream>>>(ebuf, bcur, deg, sd, W1, b1, W2, b2, x2);
    k_bounds<<<nbl, TB, 0, stream>>>(batch, gstart);
    k_pool <<<N_GRAPHS, TB, 0, stream>>>(x2, sd, W1, b1, gstart, Wl, bl, out);
}

// Round 8
// 256.956 us; speedup vs baseline: 5.1266x; 1.0203x over previous
//
#include <hip/hip_runtime.h>
#include <hip/hip_bf16.h>

#define N_NODES 100000
#define N_EDGES 3200000
#define N_GRAPHS 512
#define HID 64
#define OUT_DIM 10

#define NPB 98                  // nodes per dst-bucket
#define NB  1021                // ceil(N_NODES / NPB)
#define CAP 3584                // edges/bucket capacity (mean 3136, sd ~56 -> +8 sigma)

// ---------------------------------------------------------------------------
// K1: partition edges into dst-range buckets. Packed word: (dlocal<<24)|src.
// Block-aggregated cursors: LDS histogram -> 1 ranged global atomic per
// (block,bucket) -> LDS cursors -> append. 8 edges/thread (2 x int4) for a
// shorter per-thread atomic->store chain + more blocks for latency hiding.
__global__ __launch_bounds__(256) void k_part(const int4* __restrict__ src4,
                                              const int4* __restrict__ dst4,
                                              unsigned* __restrict__ bcur,
                                              unsigned* __restrict__ ebuf) {
    __shared__ unsigned hist[NB];
    __shared__ unsigned curs[NB];
    int tid = threadIdx.x;
    for (int i = tid; i < NB; i += 256) hist[i] = 0;
    __syncthreads();
    int4 s[2], d[2];
    int base4 = (blockIdx.x * 256 + tid) * 2;
    #pragma unroll
    for (int k = 0; k < 2; k++) {
        int i4 = base4 + k;
        if (i4 < N_EDGES / 4) { s[k] = src4[i4]; d[k] = dst4[i4]; }
        else { s[k] = make_int4(-1, -1, -1, -1); d[k] = make_int4(0, 0, 0, 0); }
    }
    #pragma unroll
    for (int k = 0; k < 2; k++) {
        if (s[k].x >= 0) {
            atomicAdd(&hist[d[k].x / NPB], 1u);
            atomicAdd(&hist[d[k].y / NPB], 1u);
            atomicAdd(&hist[d[k].z / NPB], 1u);
            atomicAdd(&hist[d[k].w / NPB], 1u);
        }
    }
    __syncthreads();
    for (int b = tid; b < NB; b += 256) {
        unsigned c = hist[b];
        curs[b] = c ? atomicAdd(&bcur[b], c) : 0u;
    }
    __syncthreads();
    #pragma unroll
    for (int k = 0; k < 2; k++) {
        if (s[k].x >= 0) {
            int ss[4] = { s[k].x, s[k].y, s[k].z, s[k].w };
            int dd[4] = { d[k].x, d[k].y, d[k].z, d[k].w };
            #pragma unroll
            for (int m = 0; m < 4; m++) {
                int b = dd[m] / NPB;
                unsigned dl = (unsigned)(dd[m] - b * NPB);
                unsigned slot = atomicAdd(&curs[b], 1u);
                ebuf[(size_t)b * CAP + slot] = (dl << 24) | (unsigned)ss[m];
            }
        }
    }
}

// ---------------------------------------------------------------------------
// K2: per-bucket degree histogram in LDS -> deg, dinv, g1.
__global__ __launch_bounds__(256) void k_buck1(const unsigned* __restrict__ ebuf,
                                               const unsigned* __restrict__ bcur,
                                               const float* __restrict__ x,
                                               unsigned* __restrict__ deg,
                                               float* __restrict__ dinv,
                                               float* __restrict__ g1) {
    __shared__ unsigned cnt[NPB];
    int b = blockIdx.x, tid = threadIdx.x;
    if (tid < NPB) cnt[tid] = 0;
    __syncthreads();
    int ec = (int)bcur[b];
    const unsigned* eb = ebuf + (size_t)b * CAP;
    for (int i = tid; i < ec; i += 256)
        atomicAdd(&cnt[eb[i] >> 24], 1u);
    __syncthreads();
    int n0 = b * NPB;
    int nn = min(NPB, N_NODES - n0);
    if (tid < nn) {
        unsigned c = cnt[tid];
        float dn = 1.0f / sqrtf((float)c + 1.0f);   // +1: self loop
        deg[n0 + tid] = c;
        dinv[n0 + tid] = dn;
        g1[n0 + tid] = dn * x[n0 + tid];
    }
}

// ---------------------------------------------------------------------------
// K3: per-bucket layer-1 scalar aggregation in LDS -> sd = (s, dinv).
__global__ __launch_bounds__(256) void k_buck2(const unsigned* __restrict__ ebuf,
                                               const unsigned* __restrict__ bcur,
                                               const float* __restrict__ g1,
                                               const float* __restrict__ dinv,
                                               const float* __restrict__ x,
                                               float2* __restrict__ sd) {
    __shared__ float sacc[NPB];
    int b = blockIdx.x, tid = threadIdx.x;
    if (tid < NPB) sacc[tid] = 0.f;
    __syncthreads();
    int ec = (int)bcur[b];
    const unsigned* eb = ebuf + (size_t)b * CAP;
    for (int i = tid; i < ec; i += 256) {
        unsigned w = eb[i];
        atomicAdd(&sacc[w >> 24], g1[w & 0x00FFFFFFu]);
    }
    __syncthreads();
    int n0 = b * NPB;
    int nn = min(NPB, N_NODES - n0);
    if (tid < nn) {
        float dn = dinv[n0 + tid];
        float s = dn * (sacc[tid] + dn * x[n0 + tid]);
        sd[n0 + tid] = make_float2(s, dn);
    }
}

// ---------------------------------------------------------------------------
// K4: per-bucket layer-2 aggregation + FUSED MEAN-POOL ACCUMULATION.
// 1) counting-sort bucket edges by dlocal into LDS,
// 2) wave-per-node: batched lane gather -> wave-private LDS stage ->
//    broadcast-read register accumulation (lane = channel),
// 3) fused self-term + W2 matvec (readlane broadcast) -> x2 row in reg,
// 4) per-graph partials of x1 (=t) and x2 in registers (batch sorted =>
//    ~1-2 graphs per bucket), flushed via global atomicAdd at boundaries.
// No x2 materialization at all.
__global__ __launch_bounds__(256) void k_buck3(const unsigned* __restrict__ ebuf,
                                               const unsigned* __restrict__ bcur,
                                               const unsigned* __restrict__ deg,
                                               const float2* __restrict__ sd,
                                               const int* __restrict__ batch,
                                               const float* __restrict__ W1,
                                               const float* __restrict__ b1,
                                               const float* __restrict__ W2,
                                               const float* __restrict__ b2,
                                               float* __restrict__ pooled1,
                                               float* __restrict__ pooled2) {
    __shared__ unsigned sorted[CAP];     // 14336 B
    __shared__ float2 stage[256];        // 4 waves x 64, wave-private slices
    __shared__ int offs[NPB + 1];
    __shared__ unsigned curs[NPB];
    int b = blockIdx.x, tid = threadIdx.x;
    int lane = tid & 63, wv = tid >> 6;
    int n0 = b * NPB;
    int nn = min(NPB, N_NODES - n0);
    if (tid == 0) {                      // serial 98-scan: negligible
        int r = 0;
        for (int i = 0; i < nn; i++) { offs[i] = r; curs[i] = (unsigned)r; r += (int)deg[n0 + i]; }
        offs[nn] = r;
    }
    float w2col[HID];
    #pragma unroll
    for (int j = 0; j < HID; j++) w2col[j] = W2[j * HID + lane];
    float w1 = W1[lane], bb1 = b1[lane], bb2 = b2[lane];
    __syncthreads();
    int ec = (int)bcur[b];
    const unsigned* eb = ebuf + (size_t)b * CAP;
    for (int i = tid; i < ec; i += 256) {           // counting-sort scatter
        unsigned w = eb[i];
        unsigned slot = atomicAdd(&curs[w >> 24], 1u);
        sorted[slot] = w;
    }
    __syncthreads();
    float2* st = stage + wv * 64;
    int curg = -1;
    float pacc1 = 0.f, pacc2 = 0.f;
    for (int n = wv; n < nn; n += 4) {
        int lo = offs[n], hi = offs[n + 1];
        float acca = 0.f, accb = 0.f;
        for (int base = lo; base < hi; base += 64) {
            int m = hi - base; if (m > 64) m = 64;
            float2 v = make_float2(0.f, 0.f);
            if (lane < m) v = sd[sorted[base + lane] & 0x00FFFFFFu];
            st[lane] = v;                 // wave-private; DS ops in-order per wave
            int k = 0;
            for (; k + 1 < m; k += 2) {
                float2 e0 = st[k];
                float2 e1 = st[k + 1];
                acca = fmaf(e0.y, fmaxf(fmaf(e0.x, w1, bb1), 0.f), acca);
                accb = fmaf(e1.y, fmaxf(fmaf(e1.x, w1, bb1), 0.f), accb);
            }
            if (k < m) {
                float2 e0 = st[k];
                acca = fmaf(e0.y, fmaxf(fmaf(e0.x, w1, bb1), 0.f), acca);
            }
        }
        float2 self = sd[n0 + n];
        float t = fmaxf(fmaf(self.x, w1, bb1), 0.f);       // = x1[n][lane]
        float a = self.y * (acca + accb + self.y * t);     // agg[n][lane]
        float acc2a = bb2, acc2b = 0.f;
        #pragma unroll
        for (int j = 0; j < HID; j += 2) {
            float aj0 = __int_as_float(__builtin_amdgcn_readlane(__float_as_int(a), j));
            float aj1 = __int_as_float(__builtin_amdgcn_readlane(__float_as_int(a), j + 1));
            acc2a = fmaf(aj0, w2col[j], acc2a);
            acc2b = fmaf(aj1, w2col[j + 1], acc2b);
        }
        float x2v = fmaxf(acc2a + acc2b, 0.f);             // = x2[n][lane]
        int g = batch[n0 + n];                              // uniform scalar load
        if (g != curg) {
            if (curg >= 0) {
                atomicAdd(&pooled1[curg * HID + lane], pacc1);
                atomicAdd(&pooled2[curg * HID + lane], pacc2);
            }
            curg = g; pacc1 = 0.f; pacc2 = 0.f;
        }
        pacc1 += t;
        pacc2 += x2v;
    }
    if (curg >= 0) {
        atomicAdd(&pooled1[curg * HID + lane], pacc1);
        atomicAdd(&pooled2[curg * HID + lane], pacc2);
    }
}

// ---------------------------------------------------------------------------
// K5: graph segment boundaries from sorted batch.
__global__ void k_bounds(const int* __restrict__ batch, int* __restrict__ gstart) {
    int i = blockIdx.x * blockDim.x + threadIdx.x;
    if (i >= N_NODES) return;
    int b = batch[i];
    if (i == 0) {
        for (int g = 0; g <= b; g++) gstart[g] = 0;
    } else {
        int pb = batch[i - 1];
        for (int g = pb + 1; g <= b; g++) gstart[g] = i;
    }
    if (i == N_NODES - 1) {
        for (int g = b + 1; g <= N_GRAPHS; g++) gstart[g] = N_NODES;
    }
}

// K6: head: pooled/cnt -> 128x10 linear. One block (128 thr) per graph.
__global__ __launch_bounds__(128) void k_head(const float* __restrict__ pooled1,
                                              const float* __restrict__ pooled2,
                                              const int* __restrict__ gstart,
                                              const float* __restrict__ Wl,
                                              const float* __restrict__ bl,
                                              float* __restrict__ out) {
    int g = blockIdx.x;
    int t = threadIdx.x;
    float denom = fmaxf((float)(gstart[g + 1] - gstart[g]), 1.f);
    __shared__ float pl[2 * HID];
    if (t < HID) pl[t] = pooled1[g * HID + t] / denom;
    else         pl[t] = pooled2[g * HID + (t - HID)] / denom;
    __syncthreads();
    if (t < OUT_DIM) {
        float r = bl[t];
        #pragma unroll 16
        for (int j = 0; j < 2 * HID; j++) r = fmaf(pl[j], Wl[j * OUT_DIM + t], r);
        out[g * OUT_DIM + t] = r;
    }
}

// ---------------------------------------------------------------------------
extern "C" void kernel_launch(void* const* d_in, const int* in_sizes, int n_in,
                              void* d_out, int out_size, void* d_ws, size_t ws_size,
                              hipStream_t stream) {
    const float* x      = (const float*)d_in[0];
    const int*   ei     = (const int*)d_in[1];           // (2, E) int32
    const int*   batch  = (const int*)d_in[2];
    const float* W1     = (const float*)d_in[3];
    const float* b1     = (const float*)d_in[4];
    const float* W2     = (const float*)d_in[5];
    const float* b2     = (const float*)d_in[6];
    const float* Wl     = (const float*)d_in[7];
    const float* bl     = (const float*)d_in[8];
    float* out = (float*)d_out;

    const int* src = ei;
    const int* dst = ei + N_EDGES;

    // workspace carve-up (256B aligned)
    char* p = (char*)d_ws;
    auto alloc = [&](size_t bytes) { void* r = (void*)p; p += (bytes + 255) & ~(size_t)255; return r; };
    unsigned* bcur    = (unsigned*)alloc(NB * 4);
    unsigned* ebuf    = (unsigned*)alloc((size_t)NB * CAP * 4);   // 14.64 MB
    unsigned* deg     = (unsigned*)alloc(N_NODES * 4);
    float*    dinv    = (float*)alloc(N_NODES * 4);
    float*    g1      = (float*)alloc(N_NODES * 4);
    float2*   sd      = (float2*)alloc((size_t)N_NODES * 8);
    float*    pooled1 = (float*)alloc((size_t)N_GRAPHS * HID * 4);
    float*    pooled2 = (float*)alloc((size_t)N_GRAPHS * HID * 4);
    int*      gstart  = (int*)alloc((N_GRAPHS + 1) * 4);

    hipMemsetAsync(bcur, 0, NB * 4, stream);
    hipMemsetAsync(pooled1, 0, (size_t)N_GRAPHS * HID * 4, stream);
    hipMemsetAsync(pooled2, 0, (size_t)N_GRAPHS * HID * 4, stream);

    const int TB = 256;
    int pbl = (N_EDGES / 8 + TB - 1) / TB;    // 8 edges per thread
    int nbl = (N_NODES + TB - 1) / TB;

    k_part <<<pbl, TB, 0, stream>>>((const int4*)src, (const int4*)dst, bcur, ebuf);
    k_buck1<<<NB, TB, 0, stream>>>(ebuf, bcur, x, deg, dinv, g1);
    k_buck2<<<NB, TB, 0, stream>>>(ebuf, bcur, g1, dinv, x, sd);
    k_bounds<<<nbl, TB, 0, stream>>>(batch, gstart);
    k_buck3<<<NB, TB, 0, stream>>>(ebuf, bcur, deg, sd, batch, W1, b1, W2, b2, pooled1, pooled2);
    k_head <<<N_GRAPHS, 128, 0, stream>>>(pooled1, pooled2, gstart, Wl, bl, out);
}